// Round 4
// baseline (441.145 us; speedup 1.0000x reference)
//
#include <hip/hip_runtime.h>

typedef __attribute__((ext_vector_type(8))) short short8;
typedef __attribute__((ext_vector_type(4))) float f32x4;

#define GLOAD16(g, l) __builtin_amdgcn_global_load_lds(                         \
    (const __attribute__((address_space(1))) void*)(g),                          \
    (__attribute__((address_space(3))) void*)(l), 16, 0, 0)

__device__ __forceinline__ float bf2f(unsigned short u) {
  union { unsigned int i; float f; } c; c.i = ((unsigned int)u) << 16; return c.f;
}
__device__ __forceinline__ unsigned short f2bf(float f) {
  union { float f; unsigned int i; } c; c.f = f;
  unsigned int u = c.i;
  u = (u + 0x7fffu + ((u >> 16) & 1u)) >> 16;
  return (unsigned short)u;
}

// ---------------------------------------------------------------- fp32 -> bf16
__global__ __launch_bounds__(256) void cvt_f32_bf16(const float* __restrict__ src,
                                                    unsigned short* __restrict__ dst,
                                                    int n8) {
  int i = blockIdx.x * 256 + threadIdx.x;
  if (i >= n8) return;
  const float4* s4 = (const float4*)src + (long)i * 2;
  float4 a = s4[0], b = s4[1];
  short8 o;
  o[0] = (short)f2bf(a.x); o[1] = (short)f2bf(a.y);
  o[2] = (short)f2bf(a.z); o[3] = (short)f2bf(a.w);
  o[4] = (short)f2bf(b.x); o[5] = (short)f2bf(b.y);
  o[6] = (short)f2bf(b.z); o[7] = (short)f2bf(b.w);
  *((short8*)dst + i) = o;
}

// ------------------------------------------------- C = A(MxK) * B(NxK)^T  (bf16)
// Deep-pipelined: BM=256 x BN=128 x BK=64, 8 waves (4M x 2N), 64x64/wave.
// Triple-buffered LDS (144KB). Iteration t: issue K-tile t+2 stages -> free buf,
// s_waitcnt vmcnt(12) (2 future tiles x 6 loads in flight, never 0 mid-loop),
// raw s_barrier, compute buf[t%3], raw s_barrier (WAR fence). Readers and
// writers of every buffer are barrier-separated -> race-free by construction.
template<int OUT_F32>
__global__ __launch_bounds__(512, 1) void gemm_bt2(const unsigned short* __restrict__ A,
                                                   const unsigned short* __restrict__ B,
                                                   void* __restrict__ Cout,
                                                   int M, int N, int K) {
  __shared__ __attribute__((aligned(16))) unsigned short Ah[3][256 * 64];  // 96KB
  __shared__ __attribute__((aligned(16))) unsigned short Bh[3][128 * 64];  // 48KB

  const int tid = threadIdx.x;
  const int l = tid & 63;
  const int w = tid >> 6;          // 0..7
  const int wm = w >> 1;           // 0..3  (row group: 64 rows each)
  const int wn = w & 1;            // 0..1  (col group: 64 cols each)

  // bijective XCD swizzle (nwg % 8 == 0 for both call sites)
  const int nwg = gridDim.x * gridDim.y;
  const int lin = blockIdx.y * gridDim.x + blockIdx.x;
  const int cpx = nwg >> 3;
  const int sw = (lin & 7) * cpx + (lin >> 3);
  const int bx = sw % gridDim.x;
  const int by = sw / gridDim.x;
  const long brow = (long)by * 256;
  const long bcol = (long)bx * 128;

  const int srow = tid >> 3;       // 0..63 (+ issue*64)
  const int sg = tid & 7;          // 16B granule
  const int lwb = w << 10;         // wave-uniform LDS lane-base offset

#define STAGE2(T) do {                                                          \
    const int bufi_ = (T) % 3;                                                  \
    const int k0_ = (T) * 64;                                                   \
    _Pragma("unroll")                                                           \
    for (int is_ = 0; is_ < 4; ++is_) {                                         \
      const int r_ = is_ * 64 + srow;                                           \
      const int gp_ = (sg ^ (r_ & 7)) * 8;                                      \
      GLOAD16(A + (brow + r_) * K + k0_ + gp_,                                  \
              (char*)&Ah[bufi_][0] + is_ * 8192 + lwb);                         \
    }                                                                           \
    _Pragma("unroll")                                                           \
    for (int is_ = 0; is_ < 2; ++is_) {                                         \
      const int r_ = is_ * 64 + srow;                                           \
      const int gp_ = (sg ^ (r_ & 7)) * 8;                                      \
      GLOAD16(B + (bcol + r_) * K + k0_ + gp_,                                  \
              (char*)&Bh[bufi_][0] + is_ * 8192 + lwb);                         \
    }                                                                           \
  } while (0)

  f32x4 acc[4][4];
#pragma unroll
  for (int i = 0; i < 4; ++i)
#pragma unroll
    for (int j = 0; j < 4; ++j) acc[i][j] = (f32x4){0.f, 0.f, 0.f, 0.f};

  const int tlast = (K >> 6) - 1;
  STAGE2(0);
  STAGE2(1);

  for (int t = 0; t <= tlast; ++t) {
    if (t + 2 <= tlast) {
      STAGE2(t + 2);
      asm volatile("s_waitcnt vmcnt(12)" ::: "memory");   // K-tile t complete
    } else if (t + 1 <= tlast) {
      asm volatile("s_waitcnt vmcnt(6)" ::: "memory");
    } else {
      asm volatile("s_waitcnt vmcnt(0)" ::: "memory");
    }
    __builtin_amdgcn_sched_barrier(0);
    __builtin_amdgcn_s_barrier();         // tile t visible to all waves
    __builtin_amdgcn_sched_barrier(0);

    const char* Ab = (const char*)&Ah[t % 3][0];
    const char* Bb = (const char*)&Bh[t % 3][0];
#pragma unroll
    for (int ks = 0; ks < 2; ++ks) {
      short8 af[4], bf[4];
#pragma unroll
      for (int mi = 0; mi < 4; ++mi) {
        const int row = wm * 64 + mi * 16 + (l & 15);
        const int byt = (row * 128 + (l >> 4) * 16 + ks * 64) ^ ((row & 7) << 4);
        af[mi] = *(const short8*)(Ab + byt);
      }
#pragma unroll
      for (int nj = 0; nj < 4; ++nj) {
        const int row = wn * 64 + nj * 16 + (l & 15);
        const int byt = (row * 128 + (l >> 4) * 16 + ks * 64) ^ ((row & 7) << 4);
        bf[nj] = *(const short8*)(Bb + byt);
      }
#pragma unroll
      for (int mi = 0; mi < 4; ++mi)
#pragma unroll
        for (int nj = 0; nj < 4; ++nj)
          acc[mi][nj] = __builtin_amdgcn_mfma_f32_16x16x32_bf16(af[mi], bf[nj],
                                                                acc[mi][nj], 0, 0, 0);
    }
    __builtin_amdgcn_sched_barrier(0);
    __builtin_amdgcn_s_barrier();         // WAR fence: all reads of buf done
  }

  const long rb = brow + wm * 64 + (l >> 4) * 4;
  const long cb = bcol + wn * 64 + (l & 15);
#pragma unroll
  for (int mi = 0; mi < 4; ++mi)
#pragma unroll
    for (int nj = 0; nj < 4; ++nj)
#pragma unroll
      for (int j = 0; j < 4; ++j) {
        const long row = rb + mi * 16 + j;
        const long col = cb + nj * 16;
        if (OUT_F32) ((float*)Cout)[row * N + col] = acc[mi][nj][j];
        else ((unsigned short*)Cout)[row * N + col] = f2bf(acc[mi][nj][j]);
      }
#undef STAGE2
}

// -------------------------------------------------- sin/cos table (2048 x 64)
__global__ __launch_bounds__(256) void sincos_tab(float* __restrict__ tab) {
  int gid = blockIdx.x * 256 + threadIdx.x;  // 131072
  int t = gid >> 6, d = gid & 63;
  float inv = expf(-(float)(2 * d) * 0.07195578415606394f);
  float ang = (float)t * inv;
  tab[2 * gid]     = sinf(ang);
  tab[2 * gid + 1] = cosf(ang);
}

// ------------------------------------------------------------- RoPE on q,k
__global__ __launch_bounds__(256) void rope_qk(unsigned short* __restrict__ qkv,
                                               const float* __restrict__ tab) {
  int gid = blockIdx.x * 256 + threadIdx.x;  // 524288
  int m = gid >> 7;
  int h = (gid >> 3) & 15;
  int db = gid & 7;
  int t = m & 2047;
  long base = (long)m * 6144 + h * 128 + db * 8;
  const float* tp = tab + ((long)(t << 6) + db * 8) * 2;
  float4 t0 = *(const float4*)(tp + 0);
  float4 t1 = *(const float4*)(tp + 4);
  float4 t2 = *(const float4*)(tp + 8);
  float4 t3 = *(const float4*)(tp + 12);
  float sj[8] = {t0.x, t0.z, t1.x, t1.z, t2.x, t2.z, t3.x, t3.z};
  float cj[8] = {t0.y, t0.w, t1.y, t1.w, t2.y, t2.w, t3.y, t3.w};

  unsigned short* qp = qkv + base;
  short8 q1 = *(short8*)qp, q2 = *(short8*)(qp + 64);
  short8 o1, o2;
#pragma unroll
  for (int j = 0; j < 8; ++j) {
    float a = bf2f((unsigned short)q1[j]), bq = bf2f((unsigned short)q2[j]);
    o1[j] = (short)f2bf(a * cj[j] - bq * sj[j]);
    o2[j] = (short)f2bf(bq * cj[j] + a * sj[j]);
  }
  *(short8*)qp = o1; *(short8*)(qp + 64) = o2;

  unsigned short* kp = qkv + base + 2048;
  short8 k1 = *(short8*)kp, k2 = *(short8*)(kp + 64);
#pragma unroll
  for (int j = 0; j < 8; ++j) {
    float a = bf2f((unsigned short)k1[j]), bk = bf2f((unsigned short)k2[j]);
    o1[j] = (short)f2bf(a * cj[j] - bk * sj[j]);
    o2[j] = (short)f2bf(bk * cj[j] + a * sj[j]);
  }
  *(short8*)kp = o1; *(short8*)(kp + 64) = o2;
}

// --------------------------------------------- V (b,t,h,d) -> Vt (bh, d, t)
__global__ __launch_bounds__(256) void transpose_v(const unsigned short* __restrict__ qkv,
                                                   unsigned short* __restrict__ vt) {
  __shared__ __attribute__((aligned(16))) unsigned short tile[32][136];
  int tid = threadIdx.x;
  int t0 = blockIdx.x * 32;
  int bh = blockIdx.y;
  int b = bh >> 4, h = bh & 15;
  {
    int tt = tid >> 3;
    int dcb = (tid & 7) * 16;
    const unsigned short* src = qkv + (long)(b * 2048 + t0 + tt) * 6144 + 4096 + h * 128 + dcb;
    *(short8*)&tile[tt][dcb]     = *(const short8*)src;
    *(short8*)&tile[tt][dcb + 8] = *(const short8*)(src + 8);
  }
  __syncthreads();
  {
    int d = tid >> 1;
    int ts = (tid & 1) * 16;
    short8 o0, o1;
#pragma unroll
    for (int i = 0; i < 8; ++i) o0[i] = (short)tile[ts + i][d];
#pragma unroll
    for (int i = 0; i < 8; ++i) o1[i] = (short)tile[ts + 8 + i][d];
    unsigned short* dst = vt + (long)bh * 262144 + (long)d * 2048 + t0 + ts;
    *(short8*)dst       = o0;
    *(short8*)(dst + 8) = o1;
  }
}

// ----------------------------------------------------------- flash attention
#define LOG2E 1.4426950408889634f
#define STAGE(IT, BUF) do {                                                     \
    const int kv0s_ = (IT) * 64;                                                \
    _Pragma("unroll")                                                           \
    for (int i_ = 0; i_ < 4; ++i_) {                                            \
      const int kr_ = (tid >> 4) + i_ * 16;                                     \
      const int kgp_ = ((tid & 15) ^ (kr_ & 7)) * 8;                            \
      GLOAD16(qkv + (long)(b * 2048 + kv0s_ + kr_) * 6144 + 2048 + h * 128 + kgp_, \
              (char*)&Kh[BUF][0] + (w << 10) + i_ * 4096);                      \
      const int vr_ = (tid >> 3) + i_ * 32;                                     \
      const int vgp_ = ((tid & 7) ^ (vr_ & 7)) * 8;                             \
      GLOAD16(vt + (long)bh * 262144 + (long)vr_ * 2048 + kv0s_ + vgp_,         \
              (char*)&Vh[BUF][0] + (w << 10) + i_ * 4096);                      \
    }                                                                           \
  } while (0)

#define COMPUTE_TILE(QF, ACC, MR, LR, Q0, PHP, BUFB) do {                       \
    f32x4 s_[4];                                                                \
    _Pragma("unroll")                                                           \
    for (int kvt_ = 0; kvt_ < 4; ++kvt_) {                                      \
      s_[kvt_] = (f32x4){0.f, 0.f, 0.f, 0.f};                                   \
      _Pragma("unroll")                                                         \
      for (int dc_ = 0; dc_ < 4; ++dc_) {                                       \
        const int krow_ = kvt_ * 16 + (l & 15);                                 \
        const int byt_ = ((krow_ * 256 + (l >> 4) * 16 + dc_ * 64)              \
                          ^ ((krow_ & 7) << 4)) + (BUFB);                       \
        short8 kf_ = *(const short8*)((const char*)Kh + byt_);                  \
        s_[kvt_] = __builtin_amdgcn_mfma_f32_16x16x32_bf16(QF[dc_], kf_,        \
                                                           s_[kvt_], 0, 0, 0);  \
      }                                                                         \
    }                                                                           \
    const int qrc_ = (Q0) + w * 16 + ((l >> 4) << 2);                           \
    float mx_[4];                                                               \
    _Pragma("unroll") for (int j_ = 0; j_ < 4; ++j_) mx_[j_] = -1e30f;          \
    _Pragma("unroll")                                                           \
    for (int kvt_ = 0; kvt_ < 4; ++kvt_) {                                      \
      const int kvcol_ = kv0 + kvt_ * 16 + (l & 15);                            \
      _Pragma("unroll")                                                         \
      for (int j_ = 0; j_ < 4; ++j_) {                                          \
        float sv_ = s_[kvt_][j_];                                               \
        if (kvcol_ > qrc_ + j_) sv_ = -1e30f;                                   \
        s_[kvt_][j_] = sv_;                                                     \
        mx_[j_] = fmaxf(mx_[j_], sv_);                                          \
      }                                                                         \
    }                                                                           \
    float alpha_[4];                                                            \
    _Pragma("unroll")                                                           \
    for (int j_ = 0; j_ < 4; ++j_) {                                            \
      float v_ = mx_[j_];                                                       \
      v_ = fmaxf(v_, __shfl_xor(v_, 1));                                        \
      v_ = fmaxf(v_, __shfl_xor(v_, 2));                                        \
      v_ = fmaxf(v_, __shfl_xor(v_, 4));                                        \
      v_ = fmaxf(v_, __shfl_xor(v_, 8));                                        \
      float mnew_ = fmaxf((MR)[j_], v_);                                        \
      alpha_[j_] = exp2f((MR)[j_] - mnew_);                                     \
      (MR)[j_] = mnew_;                                                         \
    }                                                                           \
    float ps_[4] = {0.f, 0.f, 0.f, 0.f};                                        \
    _Pragma("unroll")                                                           \
    for (int kvt_ = 0; kvt_ < 4; ++kvt_) {                                      \
      _Pragma("unroll")                                                         \
      for (int j_ = 0; j_ < 4; ++j_) {                                          \
        float p_ = exp2f(s_[kvt_][j_] - (MR)[j_]);                              \
        ps_[j_] += p_;                                                          \
        const int prow_ = ((l >> 4) << 2) + j_;                                 \
        const int pcol_ = kvt_ * 16 + (l & 15);                                 \
        const int pb_ = (prow_ * 128 + pcol_ * 2) ^ ((prow_ & 7) << 4);         \
        *(unsigned short*)((char*)(PHP) + pb_) = f2bf(p_);                      \
      }                                                                         \
    }                                                                           \
    _Pragma("unroll")                                                           \
    for (int j_ = 0; j_ < 4; ++j_) {                                            \
      float v_ = ps_[j_];                                                       \
      v_ += __shfl_xor(v_, 1);                                                  \
      v_ += __shfl_xor(v_, 2);                                                  \
      v_ += __shfl_xor(v_, 4);                                                  \
      v_ += __shfl_xor(v_, 8);                                                  \
      (LR)[j_] = (LR)[j_] * alpha_[j_] + v_;                                    \
    }                                                                           \
    asm volatile("s_waitcnt lgkmcnt(0)" ::: "memory");                          \
    __builtin_amdgcn_sched_barrier(0);                                          \
    _Pragma("unroll")                                                           \
    for (int dn_ = 0; dn_ < 8; ++dn_)                                           \
      _Pragma("unroll")                                                         \
      for (int j_ = 0; j_ < 4; ++j_) (ACC)[dn_][j_] *= alpha_[j_];              \
    _Pragma("unroll")                                                           \
    for (int half_ = 0; half_ < 2; ++half_) {                                   \
      const int prw_ = (l & 15);                                                \
      const int pb_ = (prw_ * 128 + (l >> 4) * 16 + half_ * 64)                 \
                      ^ ((prw_ & 7) << 4);                                      \
      short8 pf_ = *(const short8*)((const char*)(PHP) + pb_);                  \
      _Pragma("unroll")                                                         \
      for (int dn_ = 0; dn_ < 8; ++dn_) {                                       \
        const int vrow_ = dn_ * 16 + (l & 15);                                  \
        const int vb_ = ((vrow_ * 128 + (l >> 4) * 16 + half_ * 64)             \
                         ^ ((vrow_ & 7) << 4)) + (BUFB);                        \
        short8 vf_ = *(const short8*)((const char*)Vh + vb_);                   \
        (ACC)[dn_] = __builtin_amdgcn_mfma_f32_16x16x32_bf16(pf_, vf_,          \
                                                             (ACC)[dn_], 0, 0, 0); \
      }                                                                         \
    }                                                                           \
  } while (0)

__global__ __launch_bounds__(256, 2) void flash_attn(const unsigned short* __restrict__ qkv,
                                                     const unsigned short* __restrict__ vt,
                                                     unsigned short* __restrict__ attn) {
  __shared__ __attribute__((aligned(16))) unsigned short Kh[2][64 * 128];
  __shared__ __attribute__((aligned(16))) unsigned short Vh[2][128 * 64];
  __shared__ __attribute__((aligned(16))) unsigned short Ph[4][2][16 * 64];

  const int tid = threadIdx.x;
  const int l = tid & 63;
  const int w = tid >> 6;
  const int bh = blockIdx.y;
  const int b = bh >> 4, h = bh & 15;
  const int qtA = blockIdx.x;
  const int qtB = 31 - qtA;
  const int q0A = qtA * 64, q0B = qtB * 64;
  const int endA = q0A + 64;
  const int nIter = qtB + 1;
  const float qscale = 0.08838834764831845f * 1.4426950408889634f;

  short8 qfA[4], qfB[4];
  {
    const int qrA = q0A + w * 16 + (l & 15);
    const int qrB = q0B + w * 16 + (l & 15);
    const unsigned short* qpA = qkv + (long)(b * 2048 + qrA) * 6144 + h * 128 + (l >> 4) * 8;
    const unsigned short* qpB = qkv + (long)(b * 2048 + qrB) * 6144 + h * 128 + (l >> 4) * 8;
#pragma unroll
    for (int dc = 0; dc < 4; ++dc) {
      short8 va = *(const short8*)(qpA + dc * 32);
      short8 vb = *(const short8*)(qpB + dc * 32);
#pragma unroll
      for (int j = 0; j < 8; ++j) {
        va[j] = (short)f2bf(bf2f((unsigned short)va[j]) * qscale);
        vb[j] = (short)f2bf(bf2f((unsigned short)vb[j]) * qscale);
      }
      qfA[dc] = va; qfB[dc] = vb;
    }
  }

  f32x4 accA[8], accB[8];
#pragma unroll
  for (int i = 0; i < 8; ++i) {
    accA[i] = (f32x4){0.f, 0.f, 0.f, 0.f};
    accB[i] = (f32x4){0.f, 0.f, 0.f, 0.f};
  }
  float mA[4], lA[4], mB[4], lB[4];
#pragma unroll
  for (int j = 0; j < 4; ++j) { mA[j] = -INFINITY; lA[j] = 0.f; mB[j] = -INFINITY; lB[j] = 0.f; }

  STAGE(0, 0);
  __syncthreads();
  for (int it = 0; it < nIter; ++it) {
    const int kv0 = it * 64;
    if (it + 1 < nIter) STAGE(it + 1, (it + 1) & 1);
    const int bufb = (it & 1) * 16384;
    COMPUTE_TILE(qfB, accB, mB, lB, q0B, (char*)&Ph[w][0][0], bufb);
    if (kv0 < endA) COMPUTE_TILE(qfA, accA, mA, lA, q0A, (char*)&Ph[w][1][0], bufb);
    __syncthreads();
  }

#pragma unroll
  for (int dn = 0; dn < 8; ++dn)
#pragma unroll
    for (int j = 0; j < 4; ++j) {
      const int qrowB = q0B + w * 16 + ((l >> 4) << 2) + j;
      const int qrowA = q0A + w * 16 + ((l >> 4) << 2) + j;
      const int d = dn * 16 + (l & 15);
      attn[((long)bh * 2048 + qrowB) * 128 + d] = f2bf(accB[dn][j] / lB[j]);
      attn[((long)bh * 2048 + qrowA) * 128 + d] = f2bf(accA[dn][j] / lA[j]);
    }
}

extern "C" void kernel_launch(void* const* d_in, const int* in_sizes, int n_in,
                              void* d_out, int out_size, void* d_ws, size_t ws_size,
                              hipStream_t stream) {
  (void)in_sizes; (void)n_in; (void)out_size; (void)ws_size;
  const float* x  = (const float*)d_in[0];
  const float* qw = (const float*)d_in[1];
  const float* ow = (const float*)d_in[2];
  float* out = (float*)d_out;
  char* ws = (char*)d_ws;

  unsigned short* xb    = (unsigned short*)(ws + 0);          // 16.78 MB (phase 1)
  unsigned short* wqb   = (unsigned short*)(ws + 16777216);   // 25.17 MB (phase 1)
  unsigned short* qkvb  = (unsigned short*)(ws + 41943040);   // 50.33 MB
  float*          tabf  = (float*)(ws + 0);                   //  1.05 MB (phase 1b)
  unsigned short* vtb   = (unsigned short*)(ws + 0);          // 16.78 MB (phase 2)
  unsigned short* attnb = (unsigned short*)(ws + 16777216);   // 16.78 MB (phase 2, BHTD)
  unsigned short* wob   = (unsigned short*)(ws + 33554432);   //  8.39 MB (phase 2)

  cvt_f32_bf16<<<4096, 256, 0, stream>>>(x, xb, 1048576);
  cvt_f32_bf16<<<6144, 256, 0, stream>>>(qw, wqb, 1572864);
  gemm_bt2<0><<<dim3(48, 16), 512, 0, stream>>>(xb, wqb, (void*)qkvb, 4096, 6144, 2048);
  sincos_tab<<<512, 256, 0, stream>>>(tabf);
  cvt_f32_bf16<<<2048, 256, 0, stream>>>(ow, wob, 524288);
  rope_qk<<<2048, 256, 0, stream>>>(qkvb, tabf);
  transpose_v<<<dim3(64, 32), 256, 0, stream>>>(qkvb, vtb);
  flash_attn<<<dim3(16, 32), 256, 0, stream>>>(qkvb, vtb, attnb);
  gemm_bt2<1><<<dim3(16, 16), 512, 0, stream>>>(attnb, wob, (void*)out, 4096, 2048, 2048);
}

// Round 5
// 432.232 us; speedup vs baseline: 1.0206x; 1.0206x over previous
//
#include <hip/hip_runtime.h>

typedef __attribute__((ext_vector_type(8))) short short8;
typedef __attribute__((ext_vector_type(4))) float f32x4;

#define GLOAD16(g, l) __builtin_amdgcn_global_load_lds(                         \
    (const __attribute__((address_space(1))) void*)(g),                          \
    (__attribute__((address_space(3))) void*)(l), 16, 0, 0)

__device__ __forceinline__ float bf2f(unsigned short u) {
  union { unsigned int i; float f; } c; c.i = ((unsigned int)u) << 16; return c.f;
}
__device__ __forceinline__ unsigned short f2bf(float f) {
  union { float f; unsigned int i; } c; c.f = f;
  unsigned int u = c.i;
  u = (u + 0x7fffu + ((u >> 16) & 1u)) >> 16;
  return (unsigned short)u;
}

// ---------------------------------------------------------------- fp32 -> bf16
__global__ __launch_bounds__(256) void cvt_f32_bf16(const float* __restrict__ src,
                                                    unsigned short* __restrict__ dst,
                                                    int n8) {
  int i = blockIdx.x * 256 + threadIdx.x;
  if (i >= n8) return;
  const float4* s4 = (const float4*)src + (long)i * 2;
  float4 a = s4[0], b = s4[1];
  short8 o;
  o[0] = (short)f2bf(a.x); o[1] = (short)f2bf(a.y);
  o[2] = (short)f2bf(a.z); o[3] = (short)f2bf(a.w);
  o[4] = (short)f2bf(b.x); o[5] = (short)f2bf(b.y);
  o[6] = (short)f2bf(b.z); o[7] = (short)f2bf(b.w);
  *((short8*)dst + i) = o;
}

// ------------------------------------------------- C = A(MxK) * B(NxK)^T  (bf16)
// m97 structure (proven 867 TF here): 128x128 tile, BK=64, 4 waves, w=16
// global_load_lds, XOR swizzle both-sides. NEW: supertiled block order —
// groups of 8 columns, by-major within group. HW round-robins consecutive
// lin across XCDs => XCD x owns fixed column bxi=x: working set per XCD =
// 1 B-panel (0.5MB, L2-resident) + A streamed from L3. Index-remap only.
template<int OUT_F32>
__global__ __launch_bounds__(256) void gemm_bt(const unsigned short* __restrict__ A,
                                               const unsigned short* __restrict__ B,
                                               void* __restrict__ Cout,
                                               int M, int N, int K) {
  __shared__ __attribute__((aligned(16))) unsigned short Ah[128 * 64];
  __shared__ __attribute__((aligned(16))) unsigned short Bh[128 * 64];
  const int tid = threadIdx.x;
  const int l = tid & 63;
  const int w = tid >> 6;
  const int wm = w >> 1, wn = w & 1;

  // supertile remap (requires gridDim.x % 8 == 0): group = 8 cols x full rows
  const int lin = blockIdx.y * gridDim.x + blockIdx.x;
  const int gsz = (gridDim.y << 3);         // 8 * gridDim.y
  const int g = lin / gsz;
  const int r = lin - g * gsz;
  const int by = r >> 3;
  const int bxi = r & 7;
  const long brow = (long)by * 128;
  const long bcol = (long)((g << 3) + bxi) * 128;

  f32x4 acc[4][4];
#pragma unroll
  for (int i = 0; i < 4; ++i)
#pragma unroll
    for (int j = 0; j < 4; ++j) acc[i][j] = (f32x4){0.f, 0.f, 0.f, 0.f};

  const int srow = tid >> 3;
  const int sg = tid & 7;
  const int lwb = w << 10;

  for (int k0 = 0; k0 < K; k0 += 64) {
    __syncthreads();
#pragma unroll
    for (int i = 0; i < 4; ++i) {
      const int rr = srow + i * 32;
      const int gp = (sg ^ (rr & 7)) * 8;
      GLOAD16(A + (brow + rr) * K + k0 + gp, (char*)Ah + lwb + i * 4096);
      GLOAD16(B + (bcol + rr) * K + k0 + gp, (char*)Bh + lwb + i * 4096);
    }
    __syncthreads();
#pragma unroll
    for (int ks = 0; ks < 2; ++ks) {
      short8 af[4], bf[4];
#pragma unroll
      for (int mi = 0; mi < 4; ++mi) {
        const int row = wm * 64 + mi * 16 + (l & 15);
        const int byt = (row * 128 + (l >> 4) * 16 + ks * 64) ^ ((row & 7) << 4);
        af[mi] = *(const short8*)((const char*)Ah + byt);
      }
#pragma unroll
      for (int nj = 0; nj < 4; ++nj) {
        const int row = wn * 64 + nj * 16 + (l & 15);
        const int byt = (row * 128 + (l >> 4) * 16 + ks * 64) ^ ((row & 7) << 4);
        bf[nj] = *(const short8*)((const char*)Bh + byt);
      }
#pragma unroll
      for (int mi = 0; mi < 4; ++mi)
#pragma unroll
        for (int nj = 0; nj < 4; ++nj)
          acc[mi][nj] = __builtin_amdgcn_mfma_f32_16x16x32_bf16(af[mi], bf[nj],
                                                                acc[mi][nj], 0, 0, 0);
    }
  }

  const long rb = brow + wm * 64 + (l >> 4) * 4;
  const long cb = bcol + wn * 64 + (l & 15);
#pragma unroll
  for (int mi = 0; mi < 4; ++mi)
#pragma unroll
    for (int nj = 0; nj < 4; ++nj)
#pragma unroll
      for (int j = 0; j < 4; ++j) {
        const long row = rb + mi * 16 + j;
        const long col = cb + nj * 16;
        if (OUT_F32) ((float*)Cout)[row * N + col] = acc[mi][nj][j];
        else ((unsigned short*)Cout)[row * N + col] = f2bf(acc[mi][nj][j]);
      }
}

// -------------------------------------------------- sin/cos table (2048 x 64)
__global__ __launch_bounds__(256) void sincos_tab(float* __restrict__ tab) {
  int gid = blockIdx.x * 256 + threadIdx.x;  // 131072
  int t = gid >> 6, d = gid & 63;
  float inv = expf(-(float)(2 * d) * 0.07195578415606394f);
  float ang = (float)t * inv;
  tab[2 * gid]     = sinf(ang);
  tab[2 * gid + 1] = cosf(ang);
}

// ------------------------------------------------------------- RoPE on q,k
__global__ __launch_bounds__(256) void rope_qk(unsigned short* __restrict__ qkv,
                                               const float* __restrict__ tab) {
  int gid = blockIdx.x * 256 + threadIdx.x;  // 524288
  int m = gid >> 7;
  int h = (gid >> 3) & 15;
  int db = gid & 7;
  int t = m & 2047;
  long base = (long)m * 6144 + h * 128 + db * 8;
  const float* tp = tab + ((long)(t << 6) + db * 8) * 2;
  float4 t0 = *(const float4*)(tp + 0);
  float4 t1 = *(const float4*)(tp + 4);
  float4 t2 = *(const float4*)(tp + 8);
  float4 t3 = *(const float4*)(tp + 12);
  float sj[8] = {t0.x, t0.z, t1.x, t1.z, t2.x, t2.z, t3.x, t3.z};
  float cj[8] = {t0.y, t0.w, t1.y, t1.w, t2.y, t2.w, t3.y, t3.w};

  unsigned short* qp = qkv + base;
  short8 q1 = *(short8*)qp, q2 = *(short8*)(qp + 64);
  short8 o1, o2;
#pragma unroll
  for (int j = 0; j < 8; ++j) {
    float a = bf2f((unsigned short)q1[j]), bq = bf2f((unsigned short)q2[j]);
    o1[j] = (short)f2bf(a * cj[j] - bq * sj[j]);
    o2[j] = (short)f2bf(bq * cj[j] + a * sj[j]);
  }
  *(short8*)qp = o1; *(short8*)(qp + 64) = o2;

  unsigned short* kp = qkv + base + 2048;
  short8 k1 = *(short8*)kp, k2 = *(short8*)(kp + 64);
#pragma unroll
  for (int j = 0; j < 8; ++j) {
    float a = bf2f((unsigned short)k1[j]), bk = bf2f((unsigned short)k2[j]);
    o1[j] = (short)f2bf(a * cj[j] - bk * sj[j]);
    o2[j] = (short)f2bf(bk * cj[j] + a * sj[j]);
  }
  *(short8*)kp = o1; *(short8*)(kp + 64) = o2;
}

// --------------------------------------------- V (b,t,h,d) -> Vt (bh, d, t)
__global__ __launch_bounds__(256) void transpose_v(const unsigned short* __restrict__ qkv,
                                                   unsigned short* __restrict__ vt) {
  __shared__ __attribute__((aligned(16))) unsigned short tile[32][136];
  int tid = threadIdx.x;
  int t0 = blockIdx.x * 32;
  int bh = blockIdx.y;
  int b = bh >> 4, h = bh & 15;
  {
    int tt = tid >> 3;
    int dcb = (tid & 7) * 16;
    const unsigned short* src = qkv + (long)(b * 2048 + t0 + tt) * 6144 + 4096 + h * 128 + dcb;
    *(short8*)&tile[tt][dcb]     = *(const short8*)src;
    *(short8*)&tile[tt][dcb + 8] = *(const short8*)(src + 8);
  }
  __syncthreads();
  {
    int d = tid >> 1;
    int ts = (tid & 1) * 16;
    short8 o0, o1;
#pragma unroll
    for (int i = 0; i < 8; ++i) o0[i] = (short)tile[ts + i][d];
#pragma unroll
    for (int i = 0; i < 8; ++i) o1[i] = (short)tile[ts + 8 + i][d];
    unsigned short* dst = vt + (long)bh * 262144 + (long)d * 2048 + t0 + ts;
    *(short8*)dst       = o0;
    *(short8*)(dst + 8) = o1;
  }
}

// ----------------------------------------------------------- flash attention
// 512 blocks (16 qt-pairs x 32 bh), 4 waves; paired q-tiles share one staged
// KV stream; K/V double-buffered with prefetch; T5 setprio around MFMA
// clusters (m191: helps attn-like structures with wave role diversity).
#define LOG2E 1.4426950408889634f
#define STAGE(IT, BUF) do {                                                     \
    const int kv0s_ = (IT) * 64;                                                \
    _Pragma("unroll")                                                           \
    for (int i_ = 0; i_ < 4; ++i_) {                                            \
      const int kr_ = (tid >> 4) + i_ * 16;                                     \
      const int kgp_ = ((tid & 15) ^ (kr_ & 7)) * 8;                            \
      GLOAD16(qkv + (long)(b * 2048 + kv0s_ + kr_) * 6144 + 2048 + h * 128 + kgp_, \
              (char*)&Kh[BUF][0] + (w << 10) + i_ * 4096);                      \
      const int vr_ = (tid >> 3) + i_ * 32;                                     \
      const int vgp_ = ((tid & 7) ^ (vr_ & 7)) * 8;                             \
      GLOAD16(vt + (long)bh * 262144 + (long)vr_ * 2048 + kv0s_ + vgp_,         \
              (char*)&Vh[BUF][0] + (w << 10) + i_ * 4096);                      \
    }                                                                           \
  } while (0)

#define COMPUTE_TILE(QF, ACC, MR, LR, Q0, PHP, BUFB) do {                       \
    f32x4 s_[4];                                                                \
    __builtin_amdgcn_s_setprio(1);                                              \
    _Pragma("unroll")                                                           \
    for (int kvt_ = 0; kvt_ < 4; ++kvt_) {                                      \
      s_[kvt_] = (f32x4){0.f, 0.f, 0.f, 0.f};                                   \
      _Pragma("unroll")                                                         \
      for (int dc_ = 0; dc_ < 4; ++dc_) {                                       \
        const int krow_ = kvt_ * 16 + (l & 15);                                 \
        const int byt_ = ((krow_ * 256 + (l >> 4) * 16 + dc_ * 64)              \
                          ^ ((krow_ & 7) << 4)) + (BUFB);                       \
        short8 kf_ = *(const short8*)((const char*)Kh + byt_);                  \
        s_[kvt_] = __builtin_amdgcn_mfma_f32_16x16x32_bf16(QF[dc_], kf_,        \
                                                           s_[kvt_], 0, 0, 0);  \
      }                                                                         \
    }                                                                           \
    __builtin_amdgcn_s_setprio(0);                                              \
    const int qrc_ = (Q0) + w * 16 + ((l >> 4) << 2);                           \
    float mx_[4];                                                               \
    _Pragma("unroll") for (int j_ = 0; j_ < 4; ++j_) mx_[j_] = -1e30f;          \
    _Pragma("unroll")                                                           \
    for (int kvt_ = 0; kvt_ < 4; ++kvt_) {                                      \
      const int kvcol_ = kv0 + kvt_ * 16 + (l & 15);                            \
      _Pragma("unroll")                                                         \
      for (int j_ = 0; j_ < 4; ++j_) {                                          \
        float sv_ = s_[kvt_][j_];                                               \
        if (kvcol_ > qrc_ + j_) sv_ = -1e30f;                                   \
        s_[kvt_][j_] = sv_;                                                     \
        mx_[j_] = fmaxf(mx_[j_], sv_);                                          \
      }                                                                         \
    }                                                                           \
    float alpha_[4];                                                            \
    _Pragma("unroll")                                                           \
    for (int j_ = 0; j_ < 4; ++j_) {                                            \
      float v_ = mx_[j_];                                                       \
      v_ = fmaxf(v_, __shfl_xor(v_, 1));                                        \
      v_ = fmaxf(v_, __shfl_xor(v_, 2));                                        \
      v_ = fmaxf(v_, __shfl_xor(v_, 4));                                        \
      v_ = fmaxf(v_, __shfl_xor(v_, 8));                                        \
      float mnew_ = fmaxf((MR)[j_], v_);                                        \
      alpha_[j_] = exp2f((MR)[j_] - mnew_);                                     \
      (MR)[j_] = mnew_;                                                         \
    }                                                                           \
    float ps_[4] = {0.f, 0.f, 0.f, 0.f};                                        \
    _Pragma("unroll")                                                           \
    for (int kvt_ = 0; kvt_ < 4; ++kvt_) {                                      \
      _Pragma("unroll")                                                         \
      for (int j_ = 0; j_ < 4; ++j_) {                                          \
        float p_ = exp2f(s_[kvt_][j_] - (MR)[j_]);                              \
        ps_[j_] += p_;                                                          \
        const int prow_ = ((l >> 4) << 2) + j_;                                 \
        const int pcol_ = kvt_ * 16 + (l & 15);                                 \
        const int pb_ = (prow_ * 128 + pcol_ * 2) ^ ((prow_ & 7) << 4);         \
        *(unsigned short*)((char*)(PHP) + pb_) = f2bf(p_);                      \
      }                                                                         \
    }                                                                           \
    _Pragma("unroll")                                                           \
    for (int j_ = 0; j_ < 4; ++j_) {                                            \
      float v_ = ps_[j_];                                                       \
      v_ += __shfl_xor(v_, 1);                                                  \
      v_ += __shfl_xor(v_, 2);                                                  \
      v_ += __shfl_xor(v_, 4);                                                  \
      v_ += __shfl_xor(v_, 8);                                                  \
      (LR)[j_] = (LR)[j_] * alpha_[j_] + v_;                                    \
    }                                                                           \
    asm volatile("s_waitcnt lgkmcnt(0)" ::: "memory");                          \
    __builtin_amdgcn_sched_barrier(0);                                          \
    _Pragma("unroll")                                                           \
    for (int dn_ = 0; dn_ < 8; ++dn_)                                           \
      _Pragma("unroll")                                                         \
      for (int j_ = 0; j_ < 4; ++j_) (ACC)[dn_][j_] *= alpha_[j_];              \
    __builtin_amdgcn_s_setprio(1);                                              \
    _Pragma("unroll")                                                           \
    for (int half_ = 0; half_ < 2; ++half_) {                                   \
      const int prw_ = (l & 15);                                                \
      const int pb_ = (prw_ * 128 + (l >> 4) * 16 + half_ * 64)                 \
                      ^ ((prw_ & 7) << 4);                                      \
      short8 pf_ = *(const short8*)((const char*)(PHP) + pb_);                  \
      _Pragma("unroll")                                                         \
      for (int dn_ = 0; dn_ < 8; ++dn_) {                                       \
        const int vrow_ = dn_ * 16 + (l & 15);                                  \
        const int vb_ = ((vrow_ * 128 + (l >> 4) * 16 + half_ * 64)             \
                         ^ ((vrow_ & 7) << 4)) + (BUFB);                        \
        short8 vf_ = *(const short8*)((const char*)Vh + vb_);                   \
        (ACC)[dn_] = __builtin_amdgcn_mfma_f32_16x16x32_bf16(pf_, vf_,          \
                                                             (ACC)[dn_], 0, 0, 0); \
      }                                                                         \
    }                                                                           \
    __builtin_amdgcn_s_setprio(0);                                              \
  } while (0)

__global__ __launch_bounds__(256, 2) void flash_attn(const unsigned short* __restrict__ qkv,
                                                     const unsigned short* __restrict__ vt,
                                                     unsigned short* __restrict__ attn) {
  __shared__ __attribute__((aligned(16))) unsigned short Kh[2][64 * 128];
  __shared__ __attribute__((aligned(16))) unsigned short Vh[2][128 * 64];
  __shared__ __attribute__((aligned(16))) unsigned short Ph[4][2][16 * 64];

  const int tid = threadIdx.x;
  const int l = tid & 63;
  const int w = tid >> 6;
  const int bh = blockIdx.y;
  const int b = bh >> 4, h = bh & 15;
  const int qtA = blockIdx.x;
  const int qtB = 31 - qtA;
  const int q0A = qtA * 64, q0B = qtB * 64;
  const int endA = q0A + 64;
  const int nIter = qtB + 1;
  const float qscale = 0.08838834764831845f * 1.4426950408889634f;

  short8 qfA[4], qfB[4];
  {
    const int qrA = q0A + w * 16 + (l & 15);
    const int qrB = q0B + w * 16 + (l & 15);
    const unsigned short* qpA = qkv + (long)(b * 2048 + qrA) * 6144 + h * 128 + (l >> 4) * 8;
    const unsigned short* qpB = qkv + (long)(b * 2048 + qrB) * 6144 + h * 128 + (l >> 4) * 8;
#pragma unroll
    for (int dc = 0; dc < 4; ++dc) {
      short8 va = *(const short8*)(qpA + dc * 32);
      short8 vb = *(const short8*)(qpB + dc * 32);
#pragma unroll
      for (int j = 0; j < 8; ++j) {
        va[j] = (short)f2bf(bf2f((unsigned short)va[j]) * qscale);
        vb[j] = (short)f2bf(bf2f((unsigned short)vb[j]) * qscale);
      }
      qfA[dc] = va; qfB[dc] = vb;
    }
  }

  f32x4 accA[8], accB[8];
#pragma unroll
  for (int i = 0; i < 8; ++i) {
    accA[i] = (f32x4){0.f, 0.f, 0.f, 0.f};
    accB[i] = (f32x4){0.f, 0.f, 0.f, 0.f};
  }
  float mA[4], lA[4], mB[4], lB[4];
#pragma unroll
  for (int j = 0; j < 4; ++j) { mA[j] = -INFINITY; lA[j] = 0.f; mB[j] = -INFINITY; lB[j] = 0.f; }

  STAGE(0, 0);
  __syncthreads();
  for (int it = 0; it < nIter; ++it) {
    const int kv0 = it * 64;
    if (it + 1 < nIter) STAGE(it + 1, (it + 1) & 1);
    const int bufb = (it & 1) * 16384;
    COMPUTE_TILE(qfB, accB, mB, lB, q0B, (char*)&Ph[w][0][0], bufb);
    if (kv0 < endA) COMPUTE_TILE(qfA, accA, mA, lA, q0A, (char*)&Ph[w][1][0], bufb);
    __syncthreads();
  }

#pragma unroll
  for (int dn = 0; dn < 8; ++dn)
#pragma unroll
    for (int j = 0; j < 4; ++j) {
      const int qrowB = q0B + w * 16 + ((l >> 4) << 2) + j;
      const int qrowA = q0A + w * 16 + ((l >> 4) << 2) + j;
      const int d = dn * 16 + (l & 15);
      attn[((long)bh * 2048 + qrowB) * 128 + d] = f2bf(accB[dn][j] / lB[j]);
      attn[((long)bh * 2048 + qrowA) * 128 + d] = f2bf(accA[dn][j] / lA[j]);
    }
}

extern "C" void kernel_launch(void* const* d_in, const int* in_sizes, int n_in,
                              void* d_out, int out_size, void* d_ws, size_t ws_size,
                              hipStream_t stream) {
  (void)in_sizes; (void)n_in; (void)out_size; (void)ws_size;
  const float* x  = (const float*)d_in[0];
  const float* qw = (const float*)d_in[1];
  const float* ow = (const float*)d_in[2];
  float* out = (float*)d_out;
  char* ws = (char*)d_ws;

  unsigned short* xb    = (unsigned short*)(ws + 0);          // 16.78 MB (phase 1)
  unsigned short* wqb   = (unsigned short*)(ws + 16777216);   // 25.17 MB (phase 1)
  unsigned short* qkvb  = (unsigned short*)(ws + 41943040);   // 50.33 MB
  float*          tabf  = (float*)(ws + 0);                   //  1.05 MB (phase 1b)
  unsigned short* vtb   = (unsigned short*)(ws + 0);          // 16.78 MB (phase 2)
  unsigned short* attnb = (unsigned short*)(ws + 16777216);   // 16.78 MB (phase 2, BHTD)
  unsigned short* wob   = (unsigned short*)(ws + 33554432);   //  8.39 MB (phase 2)

  cvt_f32_bf16<<<4096, 256, 0, stream>>>(x, xb, 1048576);
  cvt_f32_bf16<<<6144, 256, 0, stream>>>(qw, wqb, 1572864);
  gemm_bt<0><<<dim3(48, 32), 256, 0, stream>>>(xb, wqb, (void*)qkvb, 4096, 6144, 2048);
  sincos_tab<<<512, 256, 0, stream>>>(tabf);
  cvt_f32_bf16<<<2048, 256, 0, stream>>>(ow, wob, 524288);
  rope_qk<<<2048, 256, 0, stream>>>(qkvb, tabf);
  transpose_v<<<dim3(64, 32), 256, 0, stream>>>(qkvb, vtb);
  flash_attn<<<dim3(16, 32), 256, 0, stream>>>(qkvb, vtb, attnb);
  gemm_bt<1><<<dim3(16, 32), 256, 0, stream>>>(attnb, wob, (void*)out, 4096, 2048, 2048);
}